// Round 1
// baseline (407.889 us; speedup 1.0000x reference)
//
#include <hip/hip_runtime.h>
#include <math.h>

#define N_NODES 50000
#define N_EDGES 800000
#define D 128          // NODE_DIM
#define DE 10          // EDGE_DIM
#define K_TOT 266      // 2*D + DE
#define TE 64          // edges per tile (CSR-consecutive)
#define N_TILES (N_EDGES / TE)       // 12500
#define ZSTRIDE 296    // bf16 per z row in LDS (288 + 8 pad; 2-way bank alias = free)
#define MSTRIDE 132    // f32 per m row: 4*MSTRIDE = 528 ≡ 16 (mod 32 banks) so the
                       // four quad groups split 2-way (free) instead of 4-way at 129
#define WP_ELEMS (9 * 16 * 64 * 8)   // packed weight elements (bf16) = 73728
#define SCAN_BLOCKS 196              // 196*256 = 50176 >= 50000
#define CSTRIDE 16     // ints per histogram bin: one 64B line per node (kills
                       // TCC line-level atomic serialization; R8 theory)

typedef __bf16 bf16x8 __attribute__((ext_vector_type(8)));
typedef __bf16 bf16x4 __attribute__((ext_vector_type(4)));
typedef __bf16 bf16x2 __attribute__((ext_vector_type(2)));
typedef float  f32x4  __attribute__((ext_vector_type(4)));

// Single-HW-instruction transcendentals (v_exp_f32 / v_log_f32 / v_rcp_f32).
__device__ __forceinline__ float fast_sigmoid(float x) {
    float t = __builtin_amdgcn_exp2f(-1.44269504089f * x);
    return __builtin_amdgcn_rcpf(1.0f + t);
}
__device__ __forceinline__ float fast_softplus(float x) {
    float t = __builtin_amdgcn_exp2f(-1.44269504089f * fabsf(x));
    return fmaxf(x, 0.0f) + 0.69314718056f * __builtin_amdgcn_logf(1.0f + t);
}

// ---- fused prep: cvt h->bf16 | pack weights | CSR histogram ----
// counts/stats/agg pre-zeroed by one hipMemsetAsync.
// [0,6250) cvt_h; [6250,6538) pack_weights; [6538,9663) hist.
__global__ __launch_bounds__(256) void prep(
    const float* __restrict__ h, const float* __restrict__ gw,
    const float* __restrict__ cw, const int* __restrict__ ei,
    __bf16* __restrict__ hb, __bf16* __restrict__ wp,
    int* __restrict__ counts)
{
    int bx = blockIdx.x, t = threadIdx.x;
    if (bx < 6250) {
        int i4 = bx * 256 + t;
        float4 v = *(const float4*)&h[(size_t)i4 * 4];
        bf16x4 o = { (__bf16)v.x, (__bf16)v.y, (__bf16)v.z, (__bf16)v.w };
        *(bf16x4*)&hb[(size_t)i4 * 4] = o;
    } else if (bx < 6538) {
        int idx = (bx - 6250) * 256 + t;
        if (idx < WP_ELEMS) {
            int j    = idx & 7;
            int lane = (idx >> 3) & 63;
            int nb   = (idx >> 9) & 15;
            int kb   = idx >> 13;
            int k    = kb * 32 + ((lane >> 4) << 3) + j;
            int col  = ((nb >> 1) << 4) + (lane & 15);
            const float* w = (nb & 1) ? cw : gw;
            float v = (k < K_TOT) ? w[k * D + col] : 0.0f;
            wp[idx] = (__bf16)v;
        }
    } else {
        int e = (bx - 6538) * 256 + t;      // exact: 3125*256 = 800000
        atomicAdd(&counts[ei[e] * CSTRIDE], 1);
    }
}

// Phase 1: per-block sums of 256 (strided) counts
__global__ __launch_bounds__(256) void scan_partials(
    const int* __restrict__ counts, int* __restrict__ bsum)
{
    __shared__ int ss[256];
    int t = threadIdx.x;
    int i = blockIdx.x * 256 + t;
    int c = (i < N_NODES) ? counts[i * CSTRIDE] : 0;
    ss[t] = c;
    __syncthreads();
    #pragma unroll
    for (int off = 1; off < 256; off <<= 1) {
        int v = (t >= off) ? ss[t - off] : 0;
        __syncthreads();
        ss[t] += v;
        __syncthreads();
    }
    if (t == 255) bsum[blockIdx.x] = ss[255];
}

// Phase 2: block base from re-scan of partials + block-local exclusive scan.
// Writes the cursor IN PLACE over counts (counts dead afterwards).
__global__ __launch_bounds__(256) void scan_final(
    int* __restrict__ counts, const int* __restrict__ bsum)
{
    __shared__ int sb[256];
    __shared__ int ss[256];
    int t = threadIdx.x;
    sb[t] = (t < SCAN_BLOCKS) ? bsum[t] : 0;
    int i = blockIdx.x * 256 + t;
    int c = (i < N_NODES) ? counts[i * CSTRIDE] : 0;
    ss[t] = c;
    __syncthreads();
    #pragma unroll
    for (int off = 1; off < 256; off <<= 1) {
        int v  = (t >= off) ? ss[t - off] : 0;
        int vb = (t >= off) ? sb[t - off] : 0;
        __syncthreads();
        ss[t] += v;
        sb[t] += vb;
        __syncthreads();
    }
    int base = blockIdx.x ? sb[blockIdx.x - 1] : 0;
    if (i < N_NODES) counts[i * CSTRIDE] = base + ss[t] - c;   // exclusive prefix
}

// Scatter: pos from strided cursor; pre-gather (src,dst,eid) into ONE int4 in
// CSR order: single 16B random sector write (vs two partial 8B+4B writes) and
// a single coalesced 16B read in the edge kernel.
__global__ __launch_bounds__(256) void csr_scatter(
    const int* __restrict__ ei, int* __restrict__ cursor,
    int4* __restrict__ sde)
{
    int e = blockIdx.x * 256 + threadIdx.x;   // grid exact: 800000
    int node = ei[e];
    int pos = atomicAdd(&cursor[node * CSTRIDE], 1);
    sde[pos] = make_int4(node, ei[N_EDGES + e], e, 0);
}

// ---- main (R5-proven tile structure, re-warped to 8 waves/block) ----
// 512 threads: wave w owns ONE (gate,cand) column-pair block (nb = 2w, 2w+1;
// cols w*16..w*16+15) over all 64 rows. Accumulator per wave drops 4x4 -> 4x2
// f32x4 (64 -> 32 acc regs), halving the ~128-reg/wave footprint that capped
// occupancy at 4 waves/SIMD. Static demand ~75-80 regs -> (512,6) cap ~85:
// 6 waves/SIMD = 3 blocks/CU = 24 waves (was 16). Total MFMA count and wp
// read volume are unchanged (nb-pair split partitions wp exactly).
__global__ __launch_bounds__(512, 6) void edge_mfma_scatter(
    const __bf16* __restrict__ hb, const int4* __restrict__ sde,
    const float* __restrict__ ef, const __bf16* __restrict__ wp,
    const float* __restrict__ gb, const float* __restrict__ cb,
    float* __restrict__ agg)
{
    __shared__ __align__(16) unsigned char smem[TE * ZSTRIDE * 2]; // 37,888 B
    __shared__ int s_eid[TE], s_src[TE], s_dst[TE];
    __bf16* zs = (__bf16*)smem;
    float*  ms = (float*)smem;       // reused after MFMA (64 x MSTRIDE f32 = 33,792 B)

    const int t  = threadIdx.x;
    const int e0 = blockIdx.x * TE;

    if (t < TE) {
        int4 p = sde[e0 + t];        // coalesced 16B — no dependent hop
        s_src[t] = p.x;
        s_dst[t] = p.y;
        s_eid[t] = p.z;
    }
    __syncthreads();

    // ---- stage z tile (bf16): h[src] rows k=0..127, h[dst] k=128..255 ----
    #pragma unroll
    for (int it = 0; it < 4; ++it) {
        int lin = it * 512 + t;
        int region = lin >> 10;            // 0 = src, 1 = dst
        int r   = (lin >> 4) & 63;
        int seg = lin & 15;
        int node = region ? s_dst[r] : s_src[r];
        bf16x8 v = *(const bf16x8*)&hb[(size_t)node * D + seg * 8];
        *(bf16x8*)&zs[r * ZSTRIDE + region * 128 + seg * 8] = v;
    }
    // k 256..287: edge_feat (float2 x5) + zero pad (22)
    if (t < TE) {
        const float* efr = &ef[(size_t)s_eid[t] * DE];   // 40B rows, 8B-aligned
        __bf16* row = &zs[t * ZSTRIDE + 256];
        #pragma unroll
        for (int j = 0; j < 5; ++j) {
            float2 a = *(const float2*)&efr[j * 2];
            bf16x2 p = { (__bf16)a.x, (__bf16)a.y };
            *(bf16x2*)&row[j * 2] = p;
        }
        *(bf16x2*)&row[10] = (bf16x2)(__bf16)0.0f;
        *(bf16x4*)&row[12] = (bf16x4)(__bf16)0.0f;
        *(bf16x8*)&row[16] = (bf16x8)(__bf16)0.0f;
        *(bf16x8*)&row[24] = (bf16x8)(__bf16)0.0f;
    }
    __syncthreads();

    // ---- MFMA: [64 x 288] @ [288 x 32] per wave (nb pair 2w, 2w+1) ----
    const int w     = t >> 6;        // 0..7: column block
    const int l     = t & 63;
    const int quad  = l >> 4;
    const int col16 = l & 15;

    f32x4 acc[4][2];
    #pragma unroll
    for (int mt = 0; mt < 4; ++mt)
        #pragma unroll
        for (int f = 0; f < 2; ++f)
            acc[mt][f] = (f32x4)0.0f;

    const __bf16* zp  = &zs[col16 * ZSTRIDE + quad * 8];
    const __bf16* wpp = &wp[(size_t)((w * 2) * 64 + l) * 8];

    #pragma unroll
    for (int kb = 0; kb < 9; ++kb) {
        bf16x8 afr[4];
        #pragma unroll
        for (int mt = 0; mt < 4; ++mt)
            afr[mt] = *(const bf16x8*)&zp[mt * 16 * ZSTRIDE + kb * 32];
        bf16x8 bfr[2];
        #pragma unroll
        for (int f = 0; f < 2; ++f)
            bfr[f] = *(const bf16x8*)&wpp[(size_t)(kb * 16 + f) * 512];
        #pragma unroll
        for (int mt = 0; mt < 4; ++mt)
            #pragma unroll
            for (int f = 0; f < 2; ++f)
                acc[mt][f] = __builtin_amdgcn_mfma_f32_16x16x32_bf16(
                    afr[mt], bfr[f], acc[mt][f], 0, 0, 0);
    }
    __syncthreads();   // all waves done reading zs; safe to overwrite as ms

    // ---- m = sigmoid(g+gb)*softplus(c+cb) -> LDS (one col per thread) ----
    const int col = w * 16 + col16;
    const float cbv = cb[col];
    const float gbn = -1.44269504089f * gb[col];   // fold bias into exp2 scale

    #pragma unroll
    for (int mt = 0; mt < 4; ++mt) {
        #pragma unroll
        for (int r = 0; r < 4; ++r) {
            int e = mt * 16 + quad * 4 + r;
            float garg = fmaf(-1.44269504089f, acc[mt][0][r], gbn);
            float sg   = __builtin_amdgcn_rcpf(1.0f + __builtin_amdgcn_exp2f(garg));
            float x    = acc[mt][1][r] + cbv;
            float tt   = __builtin_amdgcn_exp2f(-1.44269504089f * fabsf(x));
            float sp   = fmaxf(x, 0.0f) + 0.69314718056f * __builtin_amdgcn_logf(1.0f + tt);
            ms[e * MSTRIDE + col] = sg * sp;
        }
    }
    __syncthreads();

    // ---- run-segmented reduction over CSR-sorted rows, one atomic per run.
    // 512 threads = 4 row-segments x 128 cols (16 rows each).
    const int seg = t >> 7;            // 0..3
    const int c   = t & 127;
    const int rlo = seg * 16, rhi = rlo + 16;
    int   cur = s_src[rlo];
    float s   = 0.0f;
    for (int e = rlo; e < rhi; ++e) {
        int node = s_src[e];
        float v  = ms[e * MSTRIDE + c];
        if (node != cur) {
            atomicAdd(&agg[(size_t)cur * D + c], s);
            s = 0.0f; cur = node;
        }
        s += v;
    }
    atomicAdd(&agg[(size_t)cur * D + c], s);
}

__global__ __launch_bounds__(256) void col_stats(
    const float* __restrict__ agg, float* __restrict__ stats)
{
    const int t    = threadIdx.x;
    const int col  = t & 127;
    const int half = t >> 7;
    float s = 0.0f, s2 = 0.0f;
    for (int r = blockIdx.x * 2 + half; r < N_NODES; r += gridDim.x * 2) {
        float v = agg[(size_t)r * D + col];
        s += v; s2 += v * v;
    }
    atomicAdd(&stats[col], s);
    atomicAdd(&stats[128 + col], s2);
}

// BN finalize folded in: each block recomputes scale/bias from L2-hot stats.
__global__ __launch_bounds__(256) void out_softplus(
    const float* __restrict__ h, const float* __restrict__ agg,
    const float* __restrict__ stats, const float* __restrict__ gamma,
    const float* __restrict__ beta, float* __restrict__ out)
{
    __shared__ float sc[128], bi[128];
    int t = threadIdx.x;
    if (t < 128) {
        const float inv_n = 1.0f / (float)N_NODES;
        float mean = stats[t] * inv_n;
        float var  = stats[128 + t] * inv_n - mean * mean;
        var = fmaxf(var, 0.0f);
        float rstd = rsqrtf(var + 1e-5f);
        float s = rstd * gamma[t];
        sc[t] = s;
        bi[t] = beta[t] - mean * s;
    }
    __syncthreads();
    int idx4 = blockIdx.x * 256 + t;
    int base = idx4 * 4;
    if (base < N_NODES * D) {
        float4 hv = *(const float4*)&h[base];
        float4 av = *(const float4*)&agg[base];
        int c = base & 127;
        float4 o;
        o.x = fast_softplus(hv.x + av.x * sc[c + 0] + bi[c + 0]);
        o.y = fast_softplus(hv.y + av.y * sc[c + 1] + bi[c + 1]);
        o.z = fast_softplus(hv.z + av.z * sc[c + 2] + bi[c + 2]);
        o.w = fast_softplus(hv.w + av.w * sc[c + 3] + bi[c + 3]);
        *(float4*)&out[base] = o;
    }
}

extern "C" void kernel_launch(void* const* d_in, const int* in_sizes, int n_in,
                              void* d_out, int out_size, void* d_ws, size_t ws_size,
                              hipStream_t stream) {
    const float* h     = (const float*)d_in[0];
    const int*   ei    = (const int*)  d_in[1];
    const float* ef    = (const float*)d_in[2];
    const float* gw    = (const float*)d_in[3];
    const float* gb    = (const float*)d_in[4];
    const float* cw    = (const float*)d_in[5];
    const float* cb    = (const float*)d_in[6];
    const float* gamma = (const float*)d_in[7];
    const float* beta  = (const float*)d_in[8];
    float* out = (float*)d_out;

    // zeroed region first (one memset): agg | stats | counts(strided)
    float*  agg     = (float*)d_ws;                       // 25.6 MB
    float*  stats   = agg + (size_t)N_NODES * D;          // 256 f
    int*    counts  = (int*)(stats + 256);                // 3.2 MB (node*16; cursor reuses)
    int*    bsum    = counts + N_NODES * CSTRIDE;         // 256 ints
    __bf16* wp      = (__bf16*)(bsum + 256);              // 144 KB (16B-aligned)
    __bf16* hb      = wp + WP_ELEMS;                      // 12.8 MB (16B-aligned)
    int4*   sde     = (int4*)(hb + (size_t)N_NODES * D);  // 12.8 MB (16B-aligned)
    // total ~54.6 MB (< 58.6 MB proven in R2)

    const size_t zero_bytes = ((size_t)N_NODES * D + 256) * sizeof(float)
                            + (size_t)N_NODES * CSTRIDE * sizeof(int);
    hipMemsetAsync(d_ws, 0, zero_bytes, stream);
    prep<<<9663, 256, 0, stream>>>(h, gw, cw, ei, hb, wp, counts);
    scan_partials<<<SCAN_BLOCKS, 256, 0, stream>>>(counts, bsum);
    scan_final<<<SCAN_BLOCKS, 256, 0, stream>>>(counts, bsum);
    csr_scatter<<<N_EDGES / 256, 256, 0, stream>>>(ei, counts, sde);
    edge_mfma_scatter<<<N_TILES, 512, 0, stream>>>(hb, sde, ef, wp, gb, cb, agg);
    col_stats<<<784, 256, 0, stream>>>(agg, stats);
    out_softplus<<<(N_NODES * D / 4 + 255) / 256, 256, 0, stream>>>(
        h, agg, stats, gamma, beta, out);
}

// Round 2
// 375.820 us; speedup vs baseline: 1.0853x; 1.0853x over previous
//
#include <hip/hip_runtime.h>
#include <math.h>

#define N_NODES 50000
#define N_EDGES 800000
#define D 128          // NODE_DIM
#define DE 10          // EDGE_DIM
#define TE 64          // edges per tile (CSR-consecutive)
#define N_TILES (N_EDGES / TE)       // 12500
#define SST 132        // 4B words per sum/m row in LDS (128 + 4 pad; 2-way = free)
#define ASTR 136       // bf16 per A row in node_gemm LDS (granule 17 ≡ 1 mod 8: uniform)
#define OST 520        // bf16 per out row in node_gemm LDS
#define WP2_ELEMS (4 * 32 * 64 * 8)  // 65536 bf16 (128x512 packed)
#define WEF_ELEMS (16 * 64 * 8)      // 8192 bf16 (32x256 packed, k<10 live)
#define SCAN_BLOCKS 196              // 196*256 = 50176 >= 50000
#define CSTRIDE 16     // ints per histogram bin: one 64B line per node

typedef __bf16 bf16x8 __attribute__((ext_vector_type(8)));
typedef __bf16 bf16x4 __attribute__((ext_vector_type(4)));
typedef __bf16 bf16x2 __attribute__((ext_vector_type(2)));
typedef float  f32x4  __attribute__((ext_vector_type(4)));

__device__ __forceinline__ float fast_sigmoid(float x) {
    float t = __builtin_amdgcn_exp2f(-1.44269504089f * x);
    return __builtin_amdgcn_rcpf(1.0f + t);
}
__device__ __forceinline__ float fast_softplus(float x) {
    float t = __builtin_amdgcn_exp2f(-1.44269504089f * fabsf(x));
    return fmaxf(x, 0.0f) + 0.69314718056f * __builtin_amdgcn_logf(1.0f + t);
}

// ---- prep: pack node-GEMM weights | pack ef weights | CSR histogram ----
// [0,256) wp2; [256,288) wef; [288,3413) hist.
// wp2 logical cols: 0:128=gw_top, 128:256=cw_top, 256:384=gw_mid, 384:512=cw_mid.
__global__ __launch_bounds__(256) void prep(
    const float* __restrict__ gw, const float* __restrict__ cw,
    const int* __restrict__ ei,
    __bf16* __restrict__ wp2, __bf16* __restrict__ wef,
    int* __restrict__ counts)
{
    int bx = blockIdx.x, t = threadIdx.x;
    if (bx < 256) {
        int idx = bx * 256 + t;               // < 65536
        int j    = idx & 7;
        int lane = (idx >> 3) & 63;
        int nb   = (idx >> 9) & 31;
        int kb   = idx >> 14;                 // 0..3
        int k    = kb * 32 + ((lane >> 4) << 3) + j;   // 0..127
        int jp   = nb * 16 + (lane & 15);
        float v;
        if      (jp < 128) v = gw[k * D + jp];
        else if (jp < 256) v = cw[k * D + (jp - 128)];
        else if (jp < 384) v = gw[(128 + k) * D + (jp - 256)];
        else               v = cw[(128 + k) * D + (jp - 384)];
        wp2[idx] = (__bf16)v;
    } else if (bx < 288) {
        int idx = (bx - 256) * 256 + t;       // < 8192
        int j    = idx & 7;
        int lane = (idx >> 3) & 63;
        int nb   = idx >> 9;                  // 0..15 (even=gate, odd=cand)
        int k    = ((lane >> 4) << 3) + j;    // 0..31
        int col  = (nb >> 1) * 16 + (lane & 15);
        const float* w = (nb & 1) ? cw : gw;
        wef[idx] = (__bf16)((k < 10) ? w[(256 + k) * D + col] : 0.0f);
    } else {
        int e = (bx - 288) * 256 + t;         // exact: 3125*256 = 800000
        atomicAdd(&counts[ei[e] * CSTRIDE], 1);
    }
}

__global__ __launch_bounds__(256) void scan_partials(
    const int* __restrict__ counts, int* __restrict__ bsum)
{
    __shared__ int ss[256];
    int t = threadIdx.x;
    int i = blockIdx.x * 256 + t;
    int c = (i < N_NODES) ? counts[i * CSTRIDE] : 0;
    ss[t] = c;
    __syncthreads();
    #pragma unroll
    for (int off = 1; off < 256; off <<= 1) {
        int v = (t >= off) ? ss[t - off] : 0;
        __syncthreads();
        ss[t] += v;
        __syncthreads();
    }
    if (t == 255) bsum[blockIdx.x] = ss[255];
}

__global__ __launch_bounds__(256) void scan_final(
    int* __restrict__ counts, const int* __restrict__ bsum)
{
    __shared__ int sb[256];
    __shared__ int ss[256];
    int t = threadIdx.x;
    sb[t] = (t < SCAN_BLOCKS) ? bsum[t] : 0;
    int i = blockIdx.x * 256 + t;
    int c = (i < N_NODES) ? counts[i * CSTRIDE] : 0;
    ss[t] = c;
    __syncthreads();
    #pragma unroll
    for (int off = 1; off < 256; off <<= 1) {
        int v  = (t >= off) ? ss[t - off] : 0;
        int vb = (t >= off) ? sb[t - off] : 0;
        __syncthreads();
        ss[t] += v;
        sb[t] += vb;
        __syncthreads();
    }
    int base = blockIdx.x ? sb[blockIdx.x - 1] : 0;
    if (i < N_NODES) counts[i * CSTRIDE] = base + ss[t] - c;   // exclusive prefix
}

// Scatter into CSR order. src,dst < 50000 < 2^16: pack {src | dst<<16, eid}.
__global__ __launch_bounds__(256) void csr_scatter(
    const int* __restrict__ ei, int* __restrict__ cursor,
    int2* __restrict__ sde)
{
    int e = blockIdx.x * 256 + threadIdx.x;   // grid exact: 800000
    int node = ei[e];
    int pos = atomicAdd(&cursor[node * CSTRIDE], 1);
    sde[pos] = make_int2(node | (ei[N_EDGES + e] << 16), e);
}

// ---- node projection GEMM: [50048x128] @ [128x512] -> proj (bf16) ----
// cols 0:256 -> pa (in d_out), cols 256:512 -> pb (ws, aliases dead counts).
__global__ __launch_bounds__(512, 4) void node_gemm(
    const float* __restrict__ h, const __bf16* __restrict__ wp2,
    __bf16* __restrict__ pa, __bf16* __restrict__ pb)
{
    __shared__ __align__(16) __bf16 sm[64 * OST];   // 66,560 B; A-tile aliases base
    __bf16* za = sm;                                 // [64][ASTR] in phase A
    const int t  = threadIdx.x;
    const int r0 = blockIdx.x * 64;

    #pragma unroll
    for (int it = 0; it < 4; ++it) {
        int ch  = it * 512 + t;            // 2048 float4 chunks (64 rows x 32)
        int row = ch >> 5, cs = ch & 31;
        int node = r0 + row;
        float4 v = (node < N_NODES) ? *(const float4*)&h[(size_t)node * D + cs * 4]
                                    : make_float4(0.f, 0.f, 0.f, 0.f);
        bf16x4 o = { (__bf16)v.x, (__bf16)v.y, (__bf16)v.z, (__bf16)v.w };
        *(bf16x4*)&za[row * ASTR + cs * 4] = o;
    }
    __syncthreads();

    const int w = t >> 6, l = t & 63, quad = l >> 4, col16 = l & 15;
    f32x4 acc[4][4];
    #pragma unroll
    for (int mt = 0; mt < 4; ++mt)
        #pragma unroll
        for (int nt = 0; nt < 4; ++nt)
            acc[mt][nt] = (f32x4)0.0f;

    const __bf16* zp = &za[col16 * ASTR + quad * 8];
    const __bf16* bp = &wp2[(size_t)((w * 4) * 64 + l) * 8];

    #pragma unroll
    for (int kb = 0; kb < 4; ++kb) {
        bf16x8 afr[4];
        #pragma unroll
        for (int mt = 0; mt < 4; ++mt)
            afr[mt] = *(const bf16x8*)&zp[mt * 16 * ASTR + kb * 32];
        bf16x8 bfr[4];
        #pragma unroll
        for (int nt = 0; nt < 4; ++nt)
            bfr[nt] = *(const bf16x8*)&bp[(size_t)(kb * 32 + nt) * 512];
        #pragma unroll
        for (int mt = 0; mt < 4; ++mt)
            #pragma unroll
            for (int nt = 0; nt < 4; ++nt)
                acc[mt][nt] = __builtin_amdgcn_mfma_f32_16x16x32_bf16(
                    afr[mt], bfr[nt], acc[mt][nt], 0, 0, 0);
    }
    __syncthreads();   // A dead; reuse sm as out-tile

    #pragma unroll
    for (int mt = 0; mt < 4; ++mt)
        #pragma unroll
        for (int nt = 0; nt < 4; ++nt)
            #pragma unroll
            for (int r = 0; r < 4; ++r) {
                int row  = mt * 16 + quad * 4 + r;
                int colj = (w * 4 + nt) * 16 + col16;
                sm[row * OST + colj] = (__bf16)acc[mt][nt][r];
            }
    __syncthreads();

    #pragma unroll
    for (int it = 0; it < 8; ++it) {
        int ch  = it * 512 + t;            // 4096 chunks of 8 bf16 (64 rows x 64)
        int row = ch >> 6, cc = ch & 63;
        int node = r0 + row;
        if (node < N_NODES) {
            bf16x8 v = *(const bf16x8*)&sm[row * OST + cc * 8];
            int j0 = cc * 8;
            if (j0 < 256) *(bf16x8*)&pa[(size_t)node * 256 + j0]         = v;
            else          *(bf16x8*)&pb[(size_t)node * 256 + (j0 - 256)] = v;
        }
    }
}

// ---- edge kernel: gather proj sums + tiny ef-MFMA + activation + scatter ----
// Per 64-edge CSR tile: stage sum-pairs (a_g[src]+b_g[dst], a_c[src]+b_c[dst])
// as bf16x2 words in LDS; one K=32 MFMA step for ef@W_ef; activation in-place
// over the sum words (f32 m); run-segmented one-atomic-per-run scatter.
__global__ __launch_bounds__(512, 6) void edge_fuse(
    const __bf16* __restrict__ pa, const __bf16* __restrict__ pb,
    const int2* __restrict__ sde, const float* __restrict__ ef,
    const __bf16* __restrict__ wef,
    const float* __restrict__ gb, const float* __restrict__ cb,
    float* __restrict__ agg)
{
    __shared__ __align__(16) unsigned int sbuf[TE * SST];  // 33,792 B
    __shared__ __align__(16) __bf16 zE[TE * 32];           // 4 KB
    __shared__ int s_src[TE], s_dst[TE], s_eid[TE];

    const int t  = threadIdx.x;
    const int e0 = blockIdx.x * TE;
    const int w = t >> 6, l = t & 63, quad = l >> 4, col16 = l & 15;

    // early independent loads (in flight across staging)
    const __bf16* wpp = &wef[(size_t)((w * 2) * 64 + l) * 8];
    bf16x8 bfr0 = *(const bf16x8*)&wpp[0];
    bf16x8 bfr1 = *(const bf16x8*)&wpp[512];
    const int c = w * 16 + col16;
    const float gbv = gb[c], cbv = cb[c];

    if (t < TE) {
        int2 p = sde[e0 + t];
        s_src[t] = p.x & 0xFFFF;
        s_dst[t] = (p.x >> 16) & 0xFFFF;
        s_eid[t] = p.y;
    }
    __syncthreads();

    // ef rows -> zE (k 0..9 live, 10..31 zero)
    if (t < TE) {
        const float* efr = &ef[(size_t)s_eid[t] * DE];
        __bf16* row = &zE[t * 32];
        #pragma unroll
        for (int j = 0; j < 5; ++j) {
            float2 a = *(const float2*)&efr[j * 2];
            bf16x2 p = { (__bf16)a.x, (__bf16)a.y };
            *(bf16x2*)&row[j * 2] = p;
        }
        *(bf16x2*)&row[10] = (bf16x2)(__bf16)0.0f;
        *(bf16x4*)&row[12] = (bf16x4)(__bf16)0.0f;
        *(bf16x8*)&row[16] = (bf16x8)(__bf16)0.0f;
        *(bf16x8*)&row[24] = (bf16x8)(__bf16)0.0f;
    }

    // sum staging: 1024 tasks = 64 edges x 16 col-groups of 8
    #pragma unroll
    for (int it = 0; it < 2; ++it) {
        int id  = it * 512 + t;
        int e   = id >> 4, grp = id & 15;
        int src = s_src[e], dst = s_dst[e];
        int c0  = grp * 8;
        bf16x8 ag = *(const bf16x8*)&pa[(size_t)src * 256 + c0];
        bf16x8 ac = *(const bf16x8*)&pa[(size_t)src * 256 + 128 + c0];
        bf16x8 bg = *(const bf16x8*)&pb[(size_t)dst * 256 + c0];
        bf16x8 bc = *(const bf16x8*)&pb[(size_t)dst * 256 + 128 + c0];
        unsigned int wds[8];
        #pragma unroll
        for (int j = 0; j < 8; ++j) {
            float gs = (float)ag[j] + (float)bg[j];
            float cs = (float)ac[j] + (float)bc[j];
            bf16x2 pr = { (__bf16)gs, (__bf16)cs };
            wds[j] = __builtin_bit_cast(unsigned int, pr);
        }
        *(uint4*)&sbuf[e * SST + c0]     = *(const uint4*)&wds[0];
        *(uint4*)&sbuf[e * SST + c0 + 4] = *(const uint4*)&wds[4];
    }
    __syncthreads();

    // ef @ W_ef : 8 MFMA per wave (4 row-tiles x {gate,cand})
    f32x4 acc[4][2];
    #pragma unroll
    for (int mt = 0; mt < 4; ++mt) {
        const bf16x8 a = *(const bf16x8*)&zE[(mt * 16 + col16) * 32 + quad * 8];
        acc[mt][0] = __builtin_amdgcn_mfma_f32_16x16x32_bf16(a, bfr0, (f32x4)0.0f, 0, 0, 0);
        acc[mt][1] = __builtin_amdgcn_mfma_f32_16x16x32_bf16(a, bfr1, (f32x4)0.0f, 0, 0, 0);
    }

    // activation in-place: sum word -> m (f32). Owner-exclusive slot, no barrier.
    #pragma unroll
    for (int mt = 0; mt < 4; ++mt) {
        #pragma unroll
        for (int r = 0; r < 4; ++r) {
            int e = mt * 16 + quad * 4 + r;
            unsigned int u = sbuf[e * SST + c];
            float gs = __builtin_bit_cast(float, u << 16);
            float cs = __builtin_bit_cast(float, u & 0xFFFF0000u);
            float sg = fast_sigmoid(acc[mt][0][r] + gs + gbv);
            float sp = fast_softplus(acc[mt][1][r] + cs + cbv);
            ((float*)sbuf)[e * SST + c] = sg * sp;
        }
    }
    __syncthreads();

    // run-segmented reduction, one atomic per run; 4 segs x 128 cols
    const int seg = t >> 7;
    const int cc  = t & 127;
    const int rlo = seg * 16, rhi = rlo + 16;
    int   cur = s_src[rlo];
    float s   = 0.0f;
    const float* ms = (const float*)sbuf;
    for (int e = rlo; e < rhi; ++e) {
        int node = s_src[e];
        float v  = ms[e * SST + cc];
        if (node != cur) {
            atomicAdd(&agg[(size_t)cur * D + cc], s);
            s = 0.0f; cur = node;
        }
        s += v;
    }
    atomicAdd(&agg[(size_t)cur * D + cc], s);
}

__global__ __launch_bounds__(256) void col_stats(
    const float* __restrict__ agg, float* __restrict__ stats)
{
    const int t    = threadIdx.x;
    const int col  = t & 127;
    const int half = t >> 7;
    float s = 0.0f, s2 = 0.0f;
    for (int r = blockIdx.x * 2 + half; r < N_NODES; r += gridDim.x * 2) {
        float v = agg[(size_t)r * D + col];
        s += v; s2 += v * v;
    }
    atomicAdd(&stats[col], s);
    atomicAdd(&stats[128 + col], s2);
}

__global__ __launch_bounds__(256) void out_softplus(
    const float* __restrict__ h, const float* __restrict__ agg,
    const float* __restrict__ stats, const float* __restrict__ gamma,
    const float* __restrict__ beta, float* __restrict__ out)
{
    __shared__ float sc[128], bi[128];
    int t = threadIdx.x;
    if (t < 128) {
        const float inv_n = 1.0f / (float)N_NODES;
        float mean = stats[t] * inv_n;
        float var  = stats[128 + t] * inv_n - mean * mean;
        var = fmaxf(var, 0.0f);
        float rstd = rsqrtf(var + 1e-5f);
        float s = rstd * gamma[t];
        sc[t] = s;
        bi[t] = beta[t] - mean * s;
    }
    __syncthreads();
    int idx4 = blockIdx.x * 256 + t;
    int base = idx4 * 4;
    if (base < N_NODES * D) {
        float4 hv = *(const float4*)&h[base];
        float4 av = *(const float4*)&agg[base];
        int c = base & 127;
        float4 o;
        o.x = fast_softplus(hv.x + av.x * sc[c + 0] + bi[c + 0]);
        o.y = fast_softplus(hv.y + av.y * sc[c + 1] + bi[c + 1]);
        o.z = fast_softplus(hv.z + av.z * sc[c + 2] + bi[c + 2]);
        o.w = fast_softplus(hv.w + av.w * sc[c + 3] + bi[c + 3]);
        *(float4*)&out[base] = o;
    }
}

extern "C" void kernel_launch(void* const* d_in, const int* in_sizes, int n_in,
                              void* d_out, int out_size, void* d_ws, size_t ws_size,
                              hipStream_t stream) {
    const float* h     = (const float*)d_in[0];
    const int*   ei    = (const int*)  d_in[1];
    const float* ef    = (const float*)d_in[2];
    const float* gw    = (const float*)d_in[3];
    const float* gb    = (const float*)d_in[4];
    const float* cw    = (const float*)d_in[5];
    const float* cb    = (const float*)d_in[6];
    const float* gamma = (const float*)d_in[7];
    const float* beta  = (const float*)d_in[8];
    float* out = (float*)d_out;

    // Layout: [agg 25.6M][stats 1K][U: counts 3.2M+bsum -> later pb 25.6M][wp2][wef][sde 6.4M]
    float*  agg    = (float*)d_ws;
    float*  stats  = agg + (size_t)N_NODES * D;
    int*    counts = (int*)(stats + 256);                    // U base
    int*    bsum   = counts + N_NODES * CSTRIDE;
    __bf16* pb     = (__bf16*)counts;                        // aliases U after csr_scatter
    char*   afterU = (char*)counts + (size_t)N_NODES * 256 * sizeof(__bf16);  // 25.6MB
    __bf16* wp2    = (__bf16*)afterU;                        // 128 KB
    __bf16* wef    = wp2 + WP2_ELEMS;                        // 16 KB
    int2*   sde    = (int2*)(wef + WEF_ELEMS);               // 6.4 MB
    __bf16* pa     = (__bf16*)d_out;                         // 25.6 MB scratch until final kernel
    // total ws ~= 57.75 MB (< 58.6 MB proven in R2)

    const size_t zero_bytes = ((size_t)N_NODES * D + 256) * sizeof(float)
                            + (size_t)N_NODES * CSTRIDE * sizeof(int);
    hipMemsetAsync(d_ws, 0, zero_bytes, stream);
    prep<<<3413, 256, 0, stream>>>(gw, cw, ei, wp2, wef, counts);
    scan_partials<<<SCAN_BLOCKS, 256, 0, stream>>>(counts, bsum);
    scan_final<<<SCAN_BLOCKS, 256, 0, stream>>>(counts, bsum);
    csr_scatter<<<N_EDGES / 256, 256, 0, stream>>>(ei, counts, sde);
    node_gemm<<<(N_NODES + 63) / 64, 512, 0, stream>>>(h, wp2, pa, pb);   // counts dead: pb safe
    edge_fuse<<<N_TILES, 512, 0, stream>>>(pa, pb, sde, ef, wef, gb, cb, agg);
    col_stats<<<784, 256, 0, stream>>>(agg, stats);
    out_softplus<<<(N_NODES * D / 4 + 255) / 256, 256, 0, stream>>>(
        h, agg, stats, gamma, beta, out);
}